// Round 3
// baseline (1248.165 us; speedup 1.0000x reference)
//
#include <hip/hip_runtime.h>
#include <hip/hip_bf16.h>

typedef __hip_bfloat16 bf16;
typedef __attribute__((ext_vector_type(8))) short bf16x8;
typedef __attribute__((ext_vector_type(4))) float f32x4;

#define N_NODES 50000
#define N_EDGES 800000
#define DIM 128
#define QKVW 384

__device__ __forceinline__ void storeO(float* p, float v){ *p = v; }
__device__ __forceinline__ void storeO(bf16* p, float v){ *p = __float2bfloat16(v); }
__device__ __forceinline__ float bfu2f(unsigned short u){
  return __uint_as_float(((unsigned)u) << 16);
}
__device__ __forceinline__ unsigned short f2bfbits(float f){
  bf16 t = __float2bfloat16(f);
  return *reinterpret_cast<unsigned short*>(&t);
}

__global__ void fill_kernel(unsigned* __restrict__ p, unsigned val, int n){
  int i = blockIdx.x * blockDim.x + threadIdx.x;
  if (i < n) p[i] = val;
}

// batched transpose+bf16: W[l][K][M] fp32 -> Wt[l][M][K] bf16
__global__ void prep_w_kernel(const float* __restrict__ W, bf16* __restrict__ Wt,
    int K, int M, int L){
  int idx = blockIdx.x * blockDim.x + threadIdx.x;
  int tot = L * K * M;
  if (idx >= tot) return;
  int l = idx / (K * M), r = idx - l * (K * M);
  int m = r / K, k = r - m * K;
  Wt[idx] = __float2bfloat16(W[(size_t)l * K * M + (size_t)k * M + m]);
}

// qkv packed layout is [q | v | k] so attn can read q and v with one base
// pointer (v at constant +256B). k sits at +512B, read once per dst.
__global__ void prep_qkvw_kernel(const float* __restrict__ Wq, const float* __restrict__ Wk,
    const float* __restrict__ Wv, bf16* __restrict__ Wt){
  int idx = blockIdx.x * blockDim.x + threadIdx.x;
  if (idx >= 5 * QKVW * 128) return;
  int l = idx / (QKVW * 128), r = idx - l * (QKVW * 128);
  int m = r / 128, k = r - m * 128;
  const float* src = (m < 128) ? (Wq + (size_t)l * 16384 + (size_t)k * 128 + m)
                   : (m < 256) ? (Wv + (size_t)l * 16384 + (size_t)k * 128 + (m - 128))
                               : (Wk + (size_t)l * 16384 + (size_t)k * 128 + (m - 256));
  Wt[idx] = __float2bfloat16(*src);
}

__global__ void pack_qkvbias_kernel(const float* __restrict__ bq, const float* __restrict__ bk,
    const float* __restrict__ bv, float* __restrict__ bqkv){
  int i = blockIdx.x * blockDim.x + threadIdx.x;
  if (i >= 5 * QKVW) return;
  int l = i / QKVW, j = i - l * QKVW;
  float v = (j < 128) ? bq[l * 128 + j] : (j < 256) ? bv[l * 128 + j - 128] : bk[l * 128 + j - 256];
  bqkv[i] = v;
}

// ---- CSR build: hist -> 3-phase parallel scan -> scatter ----
__global__ void hist_kernel(const int* __restrict__ dst, int* __restrict__ counts, int E){
  int e = blockIdx.x * blockDim.x + threadIdx.x;
  if (e < E) atomicAdd(counts + dst[e], 1);
}

__global__ __launch_bounds__(256) void blockscan_kernel(const int* __restrict__ counts,
    int* __restrict__ rowptr, int* __restrict__ bsum, int n){
  __shared__ int buf[256];
  int t = threadIdx.x, i = blockIdx.x * 256 + t;
  int x = (i < n) ? counts[i] : 0;
  buf[t] = x; __syncthreads();
  #pragma unroll
  for (int off = 1; off < 256; off <<= 1){
    int v = (t >= off) ? buf[t - off] : 0;
    __syncthreads(); buf[t] += v; __syncthreads();
  }
  if (i < n) rowptr[i] = buf[t] - x;
  if (t == 255) bsum[blockIdx.x] = buf[255];
}

__global__ __launch_bounds__(256) void scanb_kernel(int* __restrict__ bsum, int nb){
  __shared__ int buf[256];
  int t = threadIdx.x;
  int x = (t < nb) ? bsum[t] : 0;
  buf[t] = x; __syncthreads();
  #pragma unroll
  for (int off = 1; off < 256; off <<= 1){
    int v = (t >= off) ? buf[t - off] : 0;
    __syncthreads(); buf[t] += v; __syncthreads();
  }
  if (t < nb) bsum[t] = buf[t] - x;
  if (t == nb - 1) bsum[nb] = buf[t];
}

__global__ void addoff_kernel(int* __restrict__ rowptr, const int* __restrict__ bsum,
    int n, int nb){
  int i = blockIdx.x * blockDim.x + threadIdx.x;
  if (i < n) rowptr[i] += bsum[i >> 8];
  if (i == 0) rowptr[n] = bsum[nb];
}

__global__ void scatter_kernel(const int* __restrict__ src, const int* __restrict__ dst,
    const int* __restrict__ rowptr, int* __restrict__ cursor,
    int* __restrict__ srclist, int E){
  int e = blockIdx.x * blockDim.x + threadIdx.x;
  if (e >= E) return;
  int d = dst[e];
  int pos = rowptr[d] + atomicAdd(cursor + d, 1);
  srclist[pos] = src[e];
}

// ---- gather attention v2 (verified; at ~3.4 TB/s random-gather ceiling) ----
__global__ __launch_bounds__(256) void attn_kernel(
    const int* __restrict__ rowptr, const int* __restrict__ srclist,
    const bf16* __restrict__ qkv, bf16* __restrict__ agg, int n){
  int d = blockIdx.x * 4 + (threadIdx.x >> 6);
  int lane = threadIdx.x & 63;
  if (d >= n) return;
  int eslot = lane >> 4;          // 0..3 edge slot
  int t = lane & 15;              // feature slot: elems 8t..8t+7, head = t>>1
  float kf[8];
  {
    const int4* kp = (const int4*)(qkv + (size_t)d * QKVW + 256 + t * 8);
    int4 kv = kp[0];
    const unsigned* ku = (const unsigned*)&kv;
    #pragma unroll
    for (int j = 0; j < 4; j++){
      kf[2*j]   = __uint_as_float(ku[j] << 16) * 0.25f;
      kf[2*j+1] = __uint_as_float(ku[j] & 0xffff0000u) * 0.25f;
    }
  }
  float acc[8];
  #pragma unroll
  for (int j = 0; j < 8; j++) acc[j] = 0.f;
  float den = 0.f;
  int e = rowptr[d], e1 = rowptr[d + 1];
  for (; e < e1; e += 8){
    int eeA = e + eslot, eeB = e + 4 + eslot;
    int sA = srclist[(eeA < e1) ? eeA : (e1 - 1)];
    int sB = srclist[(eeB < e1) ? eeB : (e1 - 1)];
    const int4* qpA = (const int4*)(qkv + (size_t)sA * QKVW + t * 8);
    const int4* qpB = (const int4*)(qkv + (size_t)sB * QKVW + t * 8);
    int4 qA = qpA[0];
    int4 vA = qpA[16];            // +256B = v slice
    int4 qB = qpB[0];
    int4 vB = qpB[16];
    float pA = 0.f, pB = 0.f;
    const unsigned* qa = (const unsigned*)&qA;
    const unsigned* qb = (const unsigned*)&qB;
    #pragma unroll
    for (int j = 0; j < 4; j++){
      pA = fmaf(__uint_as_float(qa[j] << 16),          kf[2*j],   pA);
      pA = fmaf(__uint_as_float(qa[j] & 0xffff0000u),  kf[2*j+1], pA);
      pB = fmaf(__uint_as_float(qb[j] << 16),          kf[2*j],   pB);
      pB = fmaf(__uint_as_float(qb[j] & 0xffff0000u),  kf[2*j+1], pB);
    }
    pA += __shfl_xor(pA, 1);      // head-pair reduce (head spans 2 lanes)
    pB += __shfl_xor(pB, 1);
    float wA = (eeA < e1) ? __expf(pA) : 0.f;
    float wB = (eeB < e1) ? __expf(pB) : 0.f;
    den += wA + wB;
    const unsigned* va = (const unsigned*)&vA;
    const unsigned* vb = (const unsigned*)&vB;
    #pragma unroll
    for (int j = 0; j < 4; j++){
      acc[2*j]   = fmaf(wA, __uint_as_float(va[j] << 16),         acc[2*j]);
      acc[2*j+1] = fmaf(wA, __uint_as_float(va[j] & 0xffff0000u), acc[2*j+1]);
      acc[2*j]   = fmaf(wB, __uint_as_float(vb[j] << 16),         acc[2*j]);
      acc[2*j+1] = fmaf(wB, __uint_as_float(vb[j] & 0xffff0000u), acc[2*j+1]);
    }
  }
  #pragma unroll
  for (int m = 16; m <= 32; m <<= 1){
    den += __shfl_xor(den, m);
    #pragma unroll
    for (int j = 0; j < 8; j++) acc[j] += __shfl_xor(acc[j], m);
  }
  if (eslot == 0){
    float inv = (den > 0.f) ? 1.f / den : 0.f;
    unsigned short o[8];
    #pragma unroll
    for (int j = 0; j < 8; j++) o[j] = f2bfbits(acc[j] * inv);
    *(int4*)(agg + (size_t)d * DIM + t * 8) = *(const int4*)o;
  }
}

// ---- fused double-GEMM: [GEMM1 (M=128) + bias + resid (+relu) -> h store]
//      -> in-block LN (row stats via shuffle + LDS) -> Ash2 (bf16, LDS only)
//      -> [GEMM2 (K=128, M=M2) + bias (+relu) -> out2nd].
// Exploits block-row-locality: each block owns rows [bm,bm+64) end-to-end.
template<int KT1, typename AT1, bool RELU1, bool RESID, int M2T, bool RELU2, typename OT2>
__global__ __launch_bounds__(256, (KT1 == 128) ? 4 : 3) void fgemm(
    const AT1* __restrict__ A, const bf16* __restrict__ W1t, const float* __restrict__ b1v,
    const float* __restrict__ resid, float* __restrict__ hout, float* __restrict__ outd,
    const float* __restrict__ lng, const float* __restrict__ lnb,
    const bf16* __restrict__ W2t, const float* __restrict__ b2v,
    OT2* __restrict__ out2nd, int n, int M2rt){
  constexpr int NKS1 = KT1 / 32;           // k-steps GEMM1
  constexpr int NMT2 = M2T / 64;           // col-tiles GEMM2
  constexpr int CPR = KT1 / 8;             // 16B chunks per A row
  constexpr int CPT = (64 * CPR) / 256;    // chunks per thread
  __shared__ short Ash[64][KT1 + 8];
  __shared__ short Ash2[64][136];
  __shared__ float2 sred[4][64];
  int tid = threadIdx.x;
  int wv = tid >> 6, lane = tid & 63;
  int l15 = lane & 15, quad = lane >> 4;
  int bm = blockIdx.x * 64;

  // W1 fragments (single buffer, 128 cols = 2 tiles loaded sequentially)
  bf16x8 wf[NKS1];
  auto loadW1 = [&](int mt){
    int col = mt * 64 + wv * 16 + l15;     // always < 128
    #pragma unroll
    for (int ks = 0; ks < NKS1; ks++){
      int4 w = *(const int4*)(W1t + (size_t)col * KT1 + ks * 32 + quad * 8);
      wf[ks] = *(bf16x8*)&w;
    }
  };
  loadW1(0);   // overlap with A staging

  // ---- stage A ----
  #pragma unroll
  for (int i = 0; i < CPT; i++){
    int c = tid + i * 256;
    int row = c / CPR, off = (c - row * CPR) * 8;
    int gr = bm + row;
    if constexpr (sizeof(AT1) == 4){
      float va[8];
      if (gr < n){
        float4 f0 = *(const float4*)(A + (size_t)gr * KT1 + off);
        float4 f1 = *(const float4*)(A + (size_t)gr * KT1 + off + 4);
        va[0]=f0.x; va[1]=f0.y; va[2]=f0.z; va[3]=f0.w;
        va[4]=f1.x; va[5]=f1.y; va[6]=f1.z; va[7]=f1.w;
      } else {
        #pragma unroll
        for (int j = 0; j < 8; j++) va[j] = 0.f;
      }
      unsigned short tmp[8];
      #pragma unroll
      for (int j = 0; j < 8; j++) tmp[j] = f2bfbits(va[j]);
      *(int4*)(&Ash[row][off]) = *(const int4*)tmp;
    } else {
      int4 av = make_int4(0, 0, 0, 0);
      if (gr < n) av = *(const int4*)(A + (size_t)gr * KT1 + off);
      *(int4*)(&Ash[row][off]) = av;
    }
  }
  __syncthreads();

  // ---- GEMM1: M=128, keep both col-tiles' acc for LN ----
  f32x4 acc[2][4];
  #pragma unroll
  for (int mt = 0; mt < 2; mt++)
    #pragma unroll
    for (int mi = 0; mi < 4; mi++) acc[mt][mi] = (f32x4){0.f, 0.f, 0.f, 0.f};
  #pragma unroll
  for (int mt = 0; mt < 2; mt++){
    if (mt) loadW1(1);
    #pragma unroll
    for (int ks = 0; ks < NKS1; ks++){
      bf16x8 bfrag = wf[ks];
      #pragma unroll
      for (int mi = 0; mi < 4; mi++){
        bf16x8 afrag = *(const bf16x8*)(&Ash[mi * 16 + l15][ks * 32 + quad * 8]);
        acc[mt][mi] = __builtin_amdgcn_mfma_f32_16x16x32_bf16(afrag, bfrag, acc[mt][mi], 0, 0, 0);
      }
    }
  }

  // ---- epilogue-1: bias + resid (+relu), store h (+dual), LN stats ----
  int colv[2] = { wv * 16 + l15, 64 + wv * 16 + l15 };
  float b1c[2] = { b1v[colv[0]], b1v[colv[1]] };
  #pragma unroll
  for (int mt = 0; mt < 2; mt++){
    #pragma unroll
    for (int mi = 0; mi < 4; mi++){
      #pragma unroll
      for (int rg = 0; rg < 4; rg++){
        int grow = bm + mi * 16 + quad * 4 + rg;
        float v = acc[mt][mi][rg] + b1c[mt];
        if (RESID && grow < n) v += resid[(size_t)grow * 128 + colv[mt]];
        if (RELU1) v = fmaxf(v, 0.f);
        acc[mt][mi][rg] = v;
        if (grow < n){
          hout[(size_t)grow * 128 + colv[mt]] = v;
          if (outd) outd[(size_t)grow * 128 + colv[mt]] = v;
        }
      }
    }
  }
  #pragma unroll
  for (int mi = 0; mi < 4; mi++){
    #pragma unroll
    for (int rg = 0; rg < 4; rg++){
      float s = acc[0][mi][rg] + acc[1][mi][rg];
      float q = acc[0][mi][rg] * acc[0][mi][rg] + acc[1][mi][rg] * acc[1][mi][rg];
      s += __shfl_xor(s, 1); q += __shfl_xor(q, 1);
      s += __shfl_xor(s, 2); q += __shfl_xor(q, 2);
      s += __shfl_xor(s, 4); q += __shfl_xor(q, 4);
      s += __shfl_xor(s, 8); q += __shfl_xor(q, 8);
      if (l15 == 0) sred[wv][mi * 16 + quad * 4 + rg] = make_float2(s, q);
    }
  }
  __syncthreads();
  if (tid < 64){
    float2 a0 = sred[0][tid], a1 = sred[1][tid], a2 = sred[2][tid], a3 = sred[3][tid];
    float s = a0.x + a1.x + a2.x + a3.x;
    float q = a0.y + a1.y + a2.y + a3.y;
    float mu = s * (1.f / 128.f);
    float var = q * (1.f / 128.f) - mu * mu;
    float rs = rsqrtf(fmaxf(var, 0.f) + 1e-5f);
    sred[0][tid] = make_float2(mu, rs);
  }
  __syncthreads();
  // apply LN -> Ash2 (bf16)
  float gg[2] = { lng[colv[0]], lng[colv[1]] };
  float bb[2] = { lnb[colv[0]], lnb[colv[1]] };
  #pragma unroll
  for (int mi = 0; mi < 4; mi++){
    #pragma unroll
    for (int rg = 0; rg < 4; rg++){
      int row = mi * 16 + quad * 4 + rg;
      float2 ms = sred[0][row];
      #pragma unroll
      for (int mt = 0; mt < 2; mt++){
        float hv = (acc[mt][mi][rg] - ms.x) * ms.y * gg[mt] + bb[mt];
        Ash2[row][colv[mt]] = (short)f2bfbits(hv);
      }
    }
  }
  __syncthreads();

  // ---- GEMM2: K=128, M=M2T (runtime M2rt), W double-buffered ----
  bf16x8 wf2[2][4];
  auto loadW2 = [&](int mt, int b){
    int col = mt * 64 + wv * 16 + l15;
    #pragma unroll
    for (int ks = 0; ks < 4; ks++){
      int4 w = make_int4(0, 0, 0, 0);
      if (col < M2rt) w = *(const int4*)(W2t + (size_t)col * 128 + ks * 32 + quad * 8);
      wf2[b][ks] = *(bf16x8*)&w;
    }
  };
  loadW2(0, 0);
  #pragma unroll
  for (int mt = 0; mt < NMT2; mt++){
    int b = mt & 1;
    if (mt + 1 < NMT2) loadW2(mt + 1, b ^ 1);
    f32x4 a2[4];
    #pragma unroll
    for (int i = 0; i < 4; i++) a2[i] = (f32x4){0.f, 0.f, 0.f, 0.f};
    #pragma unroll
    for (int ks = 0; ks < 4; ks++){
      bf16x8 bfrag = wf2[b][ks];
      #pragma unroll
      for (int mi = 0; mi < 4; mi++){
        bf16x8 afrag = *(const bf16x8*)(&Ash2[mi * 16 + l15][ks * 32 + quad * 8]);
        a2[mi] = __builtin_amdgcn_mfma_f32_16x16x32_bf16(afrag, bfrag, a2[mi], 0, 0, 0);
      }
    }
    int col = mt * 64 + wv * 16 + l15;
    if (col < M2rt){
      float bval = b2v[col];
      #pragma unroll
      for (int mi = 0; mi < 4; mi++){
        #pragma unroll
        for (int rg = 0; rg < 4; rg++){
          int grow = bm + mi * 16 + quad * 4 + rg;
          if (grow >= n) continue;
          float v = a2[mi][rg] + bval;
          if (RELU2) v = fmaxf(v, 0.f);
          storeO(out2nd + (size_t)grow * M2rt + col, v);
        }
      }
    }
  }
}

extern "C" void kernel_launch(void* const* d_in, const int* in_sizes, int n_in,
                              void* d_out, int out_size, void* d_ws, size_t ws_size,
                              hipStream_t stream) {
  const float* x    = (const float*)d_in[0];
  const int*  esrc  = (const int*)d_in[1];
  const int*  edst  = (const int*)d_in[2];
  const float* Wi   = (const float*)d_in[3];
  const float* bi   = (const float*)d_in[4];
  const float* Wq   = (const float*)d_in[5];
  const float* bq   = (const float*)d_in[6];
  const float* Wk   = (const float*)d_in[7];
  const float* bk   = (const float*)d_in[8];
  const float* Wv   = (const float*)d_in[9];
  const float* bv   = (const float*)d_in[10];
  const float* Wo   = (const float*)d_in[11];
  const float* bo   = (const float*)d_in[12];
  const float* g1   = (const float*)d_in[13];
  const float* b1   = (const float*)d_in[14];
  const float* Wf1  = (const float*)d_in[15];
  const float* bf1  = (const float*)d_in[16];
  const float* Wf2  = (const float*)d_in[17];
  const float* bf2  = (const float*)d_in[18];
  const float* gout = (const float*)d_in[19];
  const float* bout_ln = (const float*)d_in[20];
  const float* Wout = (const float*)d_in[21];
  const float* bout = (const float*)d_in[22];

  const size_t ND = (size_t)N_NODES * DIM;   // 6.4M
  float* ws = (float*)d_ws;
  float* h   = ws;                            // ND f32
  bf16* agg  = (bf16*)(ws + ND);              // ND bf16
  bf16* qkv  = (bf16*)(ws + ND + ND / 2);     // N*384 bf16
  bf16* mid  = qkv + (size_t)N_NODES * QKVW;  // N*256 bf16 (separate now!)
  float* after_mid = ws + ND + ND / 2 + ((size_t)N_NODES * (QKVW + 256)) / 2;
  bf16* Wit    = (bf16*)after_mid;                   // 128*256
  bf16* Wqkvt  = Wit + 128 * 256;                    // 5*384*128
  bf16* Wot    = Wqkvt + 5 * QKVW * 128;             // 5*128*128
  bf16* Wf1t   = Wot + 5 * 128 * 128;                // 5*256*128
  bf16* Wf2t   = Wf1t + 5 * 256 * 128;               // 5*128*256
  bf16* Woutt  = Wf2t + 5 * 128 * 256;               // 40*128
  float* bqkv  = (float*)(Woutt + 40 * 128);         // 5*384 f32
  int* rowptr  = (int*)(bqkv + 5 * QKVW);            // N+1
  int* cnt     = rowptr + N_NODES + 1;               // N
  int* bsum    = cnt + N_NODES;                      // 197
  int* srclist = bsum + 200;                         // E

  dim3 B(256);
  const int EB = (N_EDGES + 255) / 256;
  const int NB = (N_NODES + 255) / 256;
  const int NSB = (N_NODES + 255) / 256;             // 196 scan blocks
  dim3 Grow(782);

  // ---- prep ----
  prep_w_kernel<<<(1 * 256 * 128 + 255) / 256, B, 0, stream>>>(Wi, Wit, 256, 128, 1);
  prep_qkvw_kernel<<<(5 * QKVW * 128 + 255) / 256, B, 0, stream>>>(Wq, Wk, Wv, Wqkvt);
  prep_w_kernel<<<(5 * 128 * 128 + 255) / 256, B, 0, stream>>>(Wo, Wot, 128, 128, 5);
  prep_w_kernel<<<(5 * 128 * 256 + 255) / 256, B, 0, stream>>>(Wf1, Wf1t, 128, 256, 5);
  prep_w_kernel<<<(5 * 256 * 128 + 255) / 256, B, 0, stream>>>(Wf2, Wf2t, 256, 128, 5);
  prep_w_kernel<<<(1 * 128 * 40 + 255) / 256, B, 0, stream>>>(Wout, Woutt, 128, 40, 1);
  pack_qkvbias_kernel<<<(5 * QKVW + 255) / 256, B, 0, stream>>>(bq, bk, bv, bqkv);
  fill_kernel<<<NB, B, 0, stream>>>((unsigned*)cnt, 0u, N_NODES);
  hist_kernel<<<EB, B, 0, stream>>>(edst, cnt, N_EDGES);
  blockscan_kernel<<<NSB, B, 0, stream>>>(cnt, rowptr, bsum, N_NODES);
  scanb_kernel<<<1, B, 0, stream>>>(bsum, NSB);
  addoff_kernel<<<NB, B, 0, stream>>>(rowptr, bsum, N_NODES, NSB);
  fill_kernel<<<NB, B, 0, stream>>>((unsigned*)cnt, 0u, N_NODES);
  scatter_kernel<<<EB, B, 0, stream>>>(esrc, edst, rowptr, cnt, srclist, N_EDGES);

  // input-fuse: h = relu(x@Wi+bi); qkv0 = LN0(h)@Wqkv + bqkv
  fgemm<256, float, true, false, 384, false, bf16><<<Grow, B, 0, stream>>>(
      x, Wit, bi, nullptr, h, nullptr, g1, b1,
      Wqkvt, bqkv, qkv, N_NODES, QKVW);

  for (int l = 0; l < 5; l++){
    attn_kernel<<<12500, B, 0, stream>>>(rowptr, srclist, qkv, agg, N_NODES);
    // FUSE_A: h += agg@Wo+bo ; mid = relu(LN_l(h)@Wf1+bf1)
    fgemm<128, bf16, false, true, 256, true, bf16><<<Grow, B, 0, stream>>>(
        agg, Wot + (size_t)l * 128 * 128, bo + l * DIM, h, h, nullptr,
        g1 + l * DIM, b1 + l * DIM,
        Wf1t + (size_t)l * 256 * 128, bf1 + l * 2 * DIM, mid, N_NODES, 256);
    if (l < 4){
      // FUSE_B: h += mid@Wf2+bf2 ; qkv(l+1) = LN_{l+1}(h)@Wqkv + bqkv
      fgemm<256, bf16, false, true, 384, false, bf16><<<Grow, B, 0, stream>>>(
          mid, Wf2t + (size_t)l * 128 * 256, bf2 + l * DIM, h, h, nullptr,
          g1 + (l + 1) * DIM, b1 + (l + 1) * DIM,
          Wqkvt + (size_t)(l + 1) * QKVW * 128, bqkv + (l + 1) * QKVW,
          qkv, N_NODES, QKVW);
    } else {
      // FUSE_B last: h += mid@Wf2+bf2 (dual-write d_out mid section);
      // out = LN_out(h)@Wout + bout (M=40)
      fgemm<256, bf16, false, true, 64, false, float><<<Grow, B, 0, stream>>>(
          mid, Wf2t + (size_t)l * 128 * 256, bf2 + l * DIM, h, h, (float*)d_out,
          gout, bout_ln,
          Woutt, bout, ((float*)d_out) + ND, N_NODES, 40);
    }
  }
}

// Round 4
// 943.992 us; speedup vs baseline: 1.3222x; 1.3222x over previous
//
#include <hip/hip_runtime.h>
#include <hip/hip_bf16.h>

typedef __hip_bfloat16 bf16;
typedef __attribute__((ext_vector_type(8))) short bf16x8;
typedef __attribute__((ext_vector_type(4))) float f32x4;

#define N_NODES 50000
#define N_EDGES 800000
#define DIM 128
#define QKVW 384

__device__ __forceinline__ float bfu2f(unsigned short u){
  return __uint_as_float(((unsigned)u) << 16);
}
__device__ __forceinline__ unsigned short f2bfbits(float f){
  bf16 t = __float2bfloat16(f);
  return *reinterpret_cast<unsigned short*>(&t);
}

__global__ void fill_kernel(unsigned* __restrict__ p, unsigned val, int n){
  int i = blockIdx.x * blockDim.x + threadIdx.x;
  if (i < n) p[i] = val;
}

// batched transpose+bf16: W[l][K][M] fp32 -> Wt[l][M][K] bf16
__global__ void prep_w_kernel(const float* __restrict__ W, bf16* __restrict__ Wt,
    int K, int M, int L){
  int idx = blockIdx.x * blockDim.x + threadIdx.x;
  int tot = L * K * M;
  if (idx >= tot) return;
  int l = idx / (K * M), r = idx - l * (K * M);
  int m = r / K, k = r - m * K;
  Wt[idx] = __float2bfloat16(W[(size_t)l * K * M + (size_t)k * M + m]);
}

// qkv packed layout is [q | v | k] so attn can read q and v with one base
// pointer (v at constant +256B). k sits at +512B, read once per dst.
__global__ void prep_qkvw_kernel(const float* __restrict__ Wq, const float* __restrict__ Wk,
    const float* __restrict__ Wv, bf16* __restrict__ Wt){
  int idx = blockIdx.x * blockDim.x + threadIdx.x;
  if (idx >= 5 * QKVW * 128) return;
  int l = idx / (QKVW * 128), r = idx - l * (QKVW * 128);
  int m = r / 128, k = r - m * 128;
  const float* src = (m < 128) ? (Wq + (size_t)l * 16384 + (size_t)k * 128 + m)
                   : (m < 256) ? (Wv + (size_t)l * 16384 + (size_t)k * 128 + (m - 128))
                               : (Wk + (size_t)l * 16384 + (size_t)k * 128 + (m - 256));
  Wt[idx] = __float2bfloat16(*src);
}

__global__ void pack_qkvbias_kernel(const float* __restrict__ bq, const float* __restrict__ bk,
    const float* __restrict__ bv, float* __restrict__ bqkv){
  int i = blockIdx.x * blockDim.x + threadIdx.x;
  if (i >= 5 * QKVW) return;
  int l = i / QKVW, j = i - l * QKVW;
  float v = (j < 128) ? bq[l * 128 + j] : (j < 256) ? bv[l * 128 + j - 128] : bk[l * 128 + j - 256];
  bqkv[i] = v;
}

// ---- CSR build: hist -> 3-phase parallel scan -> scatter ----
__global__ void hist_kernel(const int* __restrict__ dst, int* __restrict__ counts, int E){
  int e = blockIdx.x * blockDim.x + threadIdx.x;
  if (e < E) atomicAdd(counts + dst[e], 1);
}

__global__ __launch_bounds__(256) void blockscan_kernel(const int* __restrict__ counts,
    int* __restrict__ rowptr, int* __restrict__ bsum, int n){
  __shared__ int buf[256];
  int t = threadIdx.x, i = blockIdx.x * 256 + t;
  int x = (i < n) ? counts[i] : 0;
  buf[t] = x; __syncthreads();
  #pragma unroll
  for (int off = 1; off < 256; off <<= 1){
    int v = (t >= off) ? buf[t - off] : 0;
    __syncthreads(); buf[t] += v; __syncthreads();
  }
  if (i < n) rowptr[i] = buf[t] - x;
  if (t == 255) bsum[blockIdx.x] = buf[255];
}

__global__ __launch_bounds__(256) void scanb_kernel(int* __restrict__ bsum, int nb){
  __shared__ int buf[256];
  int t = threadIdx.x;
  int x = (t < nb) ? bsum[t] : 0;
  buf[t] = x; __syncthreads();
  #pragma unroll
  for (int off = 1; off < 256; off <<= 1){
    int v = (t >= off) ? buf[t - off] : 0;
    __syncthreads(); buf[t] += v; __syncthreads();
  }
  if (t < nb) bsum[t] = buf[t] - x;
  if (t == nb - 1) bsum[nb] = buf[t];
}

__global__ void addoff_kernel(int* __restrict__ rowptr, const int* __restrict__ bsum,
    int n, int nb){
  int i = blockIdx.x * blockDim.x + threadIdx.x;
  if (i < n) rowptr[i] += bsum[i >> 8];
  if (i == 0) rowptr[n] = bsum[nb];
}

__global__ void scatter_kernel(const int* __restrict__ src, const int* __restrict__ dst,
    const int* __restrict__ rowptr, int* __restrict__ cursor,
    int* __restrict__ srclist, int E){
  int e = blockIdx.x * blockDim.x + threadIdx.x;
  if (e >= E) return;
  int d = dst[e];
  int pos = rowptr[d] + atomicAdd(cursor + d, 1);
  srclist[pos] = src[e];
}

// ---- gather attention v2 (verified; at ~3.4 TB/s random-gather ceiling) ----
__global__ __launch_bounds__(256) void attn_kernel(
    const int* __restrict__ rowptr, const int* __restrict__ srclist,
    const bf16* __restrict__ qkv, bf16* __restrict__ agg, int n){
  int d = blockIdx.x * 4 + (threadIdx.x >> 6);
  int lane = threadIdx.x & 63;
  if (d >= n) return;
  int eslot = lane >> 4;          // 0..3 edge slot
  int t = lane & 15;              // feature slot: elems 8t..8t+7, head = t>>1
  float kf[8];
  {
    const int4* kp = (const int4*)(qkv + (size_t)d * QKVW + 256 + t * 8);
    int4 kv = kp[0];
    const unsigned* ku = (const unsigned*)&kv;
    #pragma unroll
    for (int j = 0; j < 4; j++){
      kf[2*j]   = __uint_as_float(ku[j] << 16) * 0.25f;
      kf[2*j+1] = __uint_as_float(ku[j] & 0xffff0000u) * 0.25f;
    }
  }
  float acc[8];
  #pragma unroll
  for (int j = 0; j < 8; j++) acc[j] = 0.f;
  float den = 0.f;
  int e = rowptr[d], e1 = rowptr[d + 1];
  for (; e < e1; e += 8){
    int eeA = e + eslot, eeB = e + 4 + eslot;
    int sA = srclist[(eeA < e1) ? eeA : (e1 - 1)];
    int sB = srclist[(eeB < e1) ? eeB : (e1 - 1)];
    const int4* qpA = (const int4*)(qkv + (size_t)sA * QKVW + t * 8);
    const int4* qpB = (const int4*)(qkv + (size_t)sB * QKVW + t * 8);
    int4 qA = qpA[0];
    int4 vA = qpA[16];            // +256B = v slice
    int4 qB = qpB[0];
    int4 vB = qpB[16];
    float pA = 0.f, pB = 0.f;
    const unsigned* qa = (const unsigned*)&qA;
    const unsigned* qb = (const unsigned*)&qB;
    #pragma unroll
    for (int j = 0; j < 4; j++){
      pA = fmaf(__uint_as_float(qa[j] << 16),          kf[2*j],   pA);
      pA = fmaf(__uint_as_float(qa[j] & 0xffff0000u),  kf[2*j+1], pA);
      pB = fmaf(__uint_as_float(qb[j] << 16),          kf[2*j],   pB);
      pB = fmaf(__uint_as_float(qb[j] & 0xffff0000u),  kf[2*j+1], pB);
    }
    pA += __shfl_xor(pA, 1);      // head-pair reduce (head spans 2 lanes)
    pB += __shfl_xor(pB, 1);
    float wA = (eeA < e1) ? __expf(pA) : 0.f;
    float wB = (eeB < e1) ? __expf(pB) : 0.f;
    den += wA + wB;
    const unsigned* va = (const unsigned*)&vA;
    const unsigned* vb = (const unsigned*)&vB;
    #pragma unroll
    for (int j = 0; j < 4; j++){
      acc[2*j]   = fmaf(wA, __uint_as_float(va[j] << 16),         acc[2*j]);
      acc[2*j+1] = fmaf(wA, __uint_as_float(va[j] & 0xffff0000u), acc[2*j+1]);
      acc[2*j]   = fmaf(wB, __uint_as_float(vb[j] << 16),         acc[2*j]);
      acc[2*j+1] = fmaf(wB, __uint_as_float(vb[j] & 0xffff0000u), acc[2*j+1]);
    }
  }
  #pragma unroll
  for (int m = 16; m <= 32; m <<= 1){
    den += __shfl_xor(den, m);
    #pragma unroll
    for (int j = 0; j < 8; j++) acc[j] += __shfl_xor(acc[j], m);
  }
  if (eslot == 0){
    float inv = (den > 0.f) ? 1.f / den : 0.f;
    unsigned short o[8];
    #pragma unroll
    for (int j = 0; j < 8; j++) o[j] = f2bfbits(acc[j] * inv);
    *(int4*)(agg + (size_t)d * DIM + t * 8) = *(const int4*)o;
  }
}

// ---- MFMA GEMM v5: same structure as v4 (round-2, 1060us) but MFMA operands
// SWAPPED: mfma(wfrag, afrag) -> output fragment transposed so each lane owns
// 4 CONSECUTIVE output cols of one row (row=bm+rt*16+l15, cols=colb..colb+3).
// Epilogue becomes float4 resid loads + float4/int2 stores (4x fewer instrs,
// 1KB/wave store footprint). Fragment loads unchanged. Math bit-identical.
template<int KT, int MT, typename AT, bool FUSELN, bool RELU, bool RESID, typename OT>
__global__ __launch_bounds__(256, (KT == 128) ? 4 : 2) void pgemm4(
    const AT* __restrict__ A, const float* __restrict__ lng, const float* __restrict__ lnb,
    const bf16* __restrict__ Wt, const float* __restrict__ bias,
    const float* __restrict__ resid, OT* __restrict__ out, float* __restrict__ out2,
    int n, int M){
  constexpr int CPR = KT / 8;              // 16B chunks per A row
  constexpr int CPT = (64 * CPR) / 256;    // chunks per thread
  constexpr int NMT = MT / 64;             // col-tiles
  constexpr int NKS = KT / 32;             // k-steps
  __shared__ short Ash[64][KT + 8];
  int tid = threadIdx.x;
  int wv = tid >> 6, lane = tid & 63;
  int l15 = lane & 15, quad = lane >> 4;
  int bm = blockIdx.x * 64;

  bf16x8 wf[2][NKS];
  auto loadW = [&](int mt, int b){
    int col = mt * 64 + wv * 16 + l15;
    #pragma unroll
    for (int ks = 0; ks < NKS; ks++){
      int4 w = make_int4(0, 0, 0, 0);
      if (col < M) w = *(const int4*)(Wt + (size_t)col * KT + ks * 32 + quad * 8);
      wf[b][ks] = *(bf16x8*)&w;
    }
  };
  loadW(0, 0);   // prefetch first col-tile during A staging

  // stage A row-block (convert fp32->bf16, optional fused LN)
  #pragma unroll
  for (int i = 0; i < CPT; i++){
    int c = tid + i * 256;
    int row = c / CPR, off = (c - row * CPR) * 8;
    int gr = bm + row;
    if constexpr (sizeof(AT) == 4){
      float va[8];
      if (gr < n){
        float4 f0 = *(const float4*)(A + (size_t)gr * KT + off);
        float4 f1 = *(const float4*)(A + (size_t)gr * KT + off + 4);
        va[0]=f0.x; va[1]=f0.y; va[2]=f0.z; va[3]=f0.w;
        va[4]=f1.x; va[5]=f1.y; va[6]=f1.z; va[7]=f1.w;
      } else {
        #pragma unroll
        for (int j = 0; j < 8; j++) va[j] = 0.f;
      }
      if constexpr (FUSELN){  // KT==128: 16 consecutive lanes own one row
        float s = va[0]+va[1]+va[2]+va[3]+va[4]+va[5]+va[6]+va[7];
        s += __shfl_xor(s, 1); s += __shfl_xor(s, 2);
        s += __shfl_xor(s, 4); s += __shfl_xor(s, 8);
        float mu = s * (1.f / 128.f);
        float vs = 0.f;
        #pragma unroll
        for (int j = 0; j < 8; j++){ float dd = va[j] - mu; vs += dd * dd; }
        vs += __shfl_xor(vs, 1); vs += __shfl_xor(vs, 2);
        vs += __shfl_xor(vs, 4); vs += __shfl_xor(vs, 8);
        float rs = rsqrtf(vs * (1.f / 128.f) + 1e-5f);
        float4 g0 = *(const float4*)(lng + off);
        float4 g1 = *(const float4*)(lng + off + 4);
        float4 b0 = *(const float4*)(lnb + off);
        float4 b1 = *(const float4*)(lnb + off + 4);
        va[0]=(va[0]-mu)*rs*g0.x+b0.x; va[1]=(va[1]-mu)*rs*g0.y+b0.y;
        va[2]=(va[2]-mu)*rs*g0.z+b0.z; va[3]=(va[3]-mu)*rs*g0.w+b0.w;
        va[4]=(va[4]-mu)*rs*g1.x+b1.x; va[5]=(va[5]-mu)*rs*g1.y+b1.y;
        va[6]=(va[6]-mu)*rs*g1.z+b1.z; va[7]=(va[7]-mu)*rs*g1.w+b1.w;
      }
      unsigned short tmp[8];
      #pragma unroll
      for (int j = 0; j < 8; j++) tmp[j] = f2bfbits(va[j]);
      *(int4*)(&Ash[row][off]) = *(const int4*)tmp;
    } else {
      int4 av = make_int4(0, 0, 0, 0);
      if (gr < n) av = *(const int4*)(A + (size_t)gr * KT + off);
      *(int4*)(&Ash[row][off]) = av;
    }
  }
  __syncthreads();

  #pragma unroll
  for (int mt = 0; mt < NMT; mt++){
    int b = mt & 1;
    if (mt + 1 < NMT) loadW(mt + 1, b ^ 1);   // prefetch next tile's W
    f32x4 acc[4];
    #pragma unroll
    for (int i = 0; i < 4; i++) acc[i] = (f32x4){0.f, 0.f, 0.f, 0.f};
    #pragma unroll
    for (int ks = 0; ks < NKS; ks++){
      bf16x8 bfrag = wf[b][ks];
      #pragma unroll
      for (int rt = 0; rt < 4; rt++){
        bf16x8 afrag = *(const bf16x8*)(&Ash[rt * 16 + l15][ks * 32 + quad * 8]);
        // SWAPPED operands: D[wcol][arow]; lane owns row=rt*16+l15,
        // cols = mt*64 + wv*16 + quad*4 + reg (4 consecutive).
        acc[rt] = __builtin_amdgcn_mfma_f32_16x16x32_bf16(bfrag, afrag, acc[rt], 0, 0, 0);
      }
    }
    int colb = mt * 64 + wv * 16 + quad * 4;   // base col of this lane's 4 regs
    if (colb < M){
      float4 bv4 = *(const float4*)(bias + colb);
      #pragma unroll
      for (int rt = 0; rt < 4; rt++){
        int grow = bm + rt * 16 + l15;
        if (grow >= n) continue;
        float4 v;
        v.x = acc[rt][0] + bv4.x; v.y = acc[rt][1] + bv4.y;
        v.z = acc[rt][2] + bv4.z; v.w = acc[rt][3] + bv4.w;
        if (RELU){
          v.x = fmaxf(v.x, 0.f); v.y = fmaxf(v.y, 0.f);
          v.z = fmaxf(v.z, 0.f); v.w = fmaxf(v.w, 0.f);
        }
        if (RESID){
          float4 r = *(const float4*)(resid + (size_t)grow * M + colb);
          v.x += r.x; v.y += r.y; v.z += r.z; v.w += r.w;
        }
        if constexpr (sizeof(OT) == 4){
          *(float4*)((float*)out + (size_t)grow * M + colb) = v;
        } else {
          unsigned short o[4];
          o[0] = f2bfbits(v.x); o[1] = f2bfbits(v.y);
          o[2] = f2bfbits(v.z); o[3] = f2bfbits(v.w);
          *(int2*)((bf16*)out + (size_t)grow * M + colb) = *(const int2*)o;
        }
        if (out2) *(float4*)(out2 + (size_t)grow * M + colb) = v;
      }
    }
  }
}

extern "C" void kernel_launch(void* const* d_in, const int* in_sizes, int n_in,
                              void* d_out, int out_size, void* d_ws, size_t ws_size,
                              hipStream_t stream) {
  const float* x    = (const float*)d_in[0];
  const int*  esrc  = (const int*)d_in[1];
  const int*  edst  = (const int*)d_in[2];
  const float* Wi   = (const float*)d_in[3];
  const float* bi   = (const float*)d_in[4];
  const float* Wq   = (const float*)d_in[5];
  const float* bq   = (const float*)d_in[6];
  const float* Wk   = (const float*)d_in[7];
  const float* bk   = (const float*)d_in[8];
  const float* Wv   = (const float*)d_in[9];
  const float* bv   = (const float*)d_in[10];
  const float* Wo   = (const float*)d_in[11];
  const float* bo   = (const float*)d_in[12];
  const float* g1   = (const float*)d_in[13];
  const float* b1   = (const float*)d_in[14];
  const float* Wf1  = (const float*)d_in[15];
  const float* bf1  = (const float*)d_in[16];
  const float* Wf2  = (const float*)d_in[17];
  const float* bf2  = (const float*)d_in[18];
  const float* gout = (const float*)d_in[19];
  const float* bout_ln = (const float*)d_in[20];
  const float* Wout = (const float*)d_in[21];
  const float* bout = (const float*)d_in[22];

  const size_t ND = (size_t)N_NODES * DIM;   // 6.4M
  float* ws = (float*)d_ws;
  float* h   = ws;                            // ND f32
  bf16* agg  = (bf16*)(ws + ND);              // ND bf16
  bf16* qkv  = (bf16*)(ws + ND + ND / 2);     // N*384 bf16
  bf16* mid  = qkv;                           // overlay [N,256] bf16
  float* after_qkv = ws + ND + ND / 2 + ((size_t)N_NODES * QKVW) / 2;
  bf16* Wit    = (bf16*)after_qkv;                   // 128*256
  bf16* Wqkvt  = Wit + 128 * 256;                    // 5*384*128
  bf16* Wot    = Wqkvt + 5 * QKVW * 128;             // 5*128*128
  bf16* Wf1t   = Wot + 5 * 128 * 128;                // 5*256*128
  bf16* Wf2t   = Wf1t + 5 * 256 * 128;               // 5*128*256
  bf16* Woutt  = Wf2t + 5 * 128 * 256;               // 40*128
  float* bqkv  = (float*)(Woutt + 40 * 128);         // 5*384 f32
  int* rowptr  = (int*)(bqkv + 5 * QKVW);            // N+1
  int* cnt     = rowptr + N_NODES + 1;               // N
  int* bsum    = cnt + N_NODES;                      // 197
  int* srclist = bsum + 200;                         // E

  dim3 B(256);
  const int EB = (N_EDGES + 255) / 256;
  const int NB = (N_NODES + 255) / 256;
  const int NSB = (N_NODES + 255) / 256;             // 196 scan blocks
  dim3 Grow(782);

  // ---- prep ----
  prep_w_kernel<<<(1 * 256 * 128 + 255) / 256, B, 0, stream>>>(Wi, Wit, 256, 128, 1);
  prep_qkvw_kernel<<<(5 * QKVW * 128 + 255) / 256, B, 0, stream>>>(Wq, Wk, Wv, Wqkvt);
  prep_w_kernel<<<(5 * 128 * 128 + 255) / 256, B, 0, stream>>>(Wo, Wot, 128, 128, 5);
  prep_w_kernel<<<(5 * 128 * 256 + 255) / 256, B, 0, stream>>>(Wf1, Wf1t, 128, 256, 5);
  prep_w_kernel<<<(5 * 256 * 128 + 255) / 256, B, 0, stream>>>(Wf2, Wf2t, 256, 128, 5);
  prep_w_kernel<<<(1 * 128 * 40 + 255) / 256, B, 0, stream>>>(Wout, Woutt, 128, 40, 1);
  pack_qkvbias_kernel<<<(5 * QKVW + 255) / 256, B, 0, stream>>>(bq, bk, bv, bqkv);
  fill_kernel<<<NB, B, 0, stream>>>((unsigned*)cnt, 0u, N_NODES);
  hist_kernel<<<EB, B, 0, stream>>>(edst, cnt, N_EDGES);
  blockscan_kernel<<<NSB, B, 0, stream>>>(cnt, rowptr, bsum, N_NODES);
  scanb_kernel<<<1, B, 0, stream>>>(bsum, NSB);
  addoff_kernel<<<NB, B, 0, stream>>>(rowptr, bsum, N_NODES, NSB);
  fill_kernel<<<NB, B, 0, stream>>>((unsigned*)cnt, 0u, N_NODES);
  scatter_kernel<<<EB, B, 0, stream>>>(esrc, edst, rowptr, cnt, srclist, N_EDGES);

  // h = relu(x @ Wi + bi)
  pgemm4<256, 128, float, false, true, false, float><<<Grow, B, 0, stream>>>(
      x, nullptr, nullptr, Wit, bi, nullptr, h, nullptr, N_NODES, 128);

  for (int l = 0; l < 5; l++){
    // qkv = LN(h) @ [Wq|Wv|Wk] + bias  (LN fused)
    pgemm4<128, 384, float, true, false, false, bf16><<<Grow, B, 0, stream>>>(
        h, g1 + l * DIM, b1 + l * DIM, Wqkvt + (size_t)l * QKVW * 128,
        bqkv + l * QKVW, nullptr, qkv, nullptr, N_NODES, QKVW);
    attn_kernel<<<12500, B, 0, stream>>>(rowptr, srclist, qkv, agg, N_NODES);
    // h = h + agg @ Wo + bo
    pgemm4<128, 128, bf16, false, false, true, float><<<Grow, B, 0, stream>>>(
        agg, nullptr, nullptr, Wot + (size_t)l * 128 * 128, bo + l * DIM,
        h, h, nullptr, N_NODES, 128);
    // mid = relu(LN(h) @ Wf1 + bf1)  (reference reuses g1/b1)
    pgemm4<128, 256, float, true, true, false, bf16><<<Grow, B, 0, stream>>>(
        h, g1 + l * DIM, b1 + l * DIM, Wf1t + (size_t)l * 256 * 128,
        bf1 + l * 2 * DIM, nullptr, mid, nullptr, N_NODES, 256);
    // h = h + mid @ Wf2 + bf2 ; last layer dual-writes d_out (mid output)
    float* out2 = (l == 4) ? (float*)d_out : nullptr;
    pgemm4<256, 128, bf16, false, false, true, float><<<Grow, B, 0, stream>>>(
        mid, nullptr, nullptr, Wf2t + (size_t)l * 128 * 256, bf2 + l * DIM,
        h, h, out2, N_NODES, 128);
  }

  // out = LN(h, g_out, b_out) @ Wout + bout  (M=40)
  pgemm4<128, 64, float, true, false, false, float><<<Grow, B, 0, stream>>>(
      h, gout, bout_ln, Woutt, bout, nullptr, ((float*)d_out) + ND, nullptr, N_NODES, 40);
}

// Round 5
// 937.694 us; speedup vs baseline: 1.3311x; 1.0067x over previous
//
#include <hip/hip_runtime.h>
#include <hip/hip_bf16.h>

typedef __hip_bfloat16 bf16;
typedef __attribute__((ext_vector_type(8))) short bf16x8;
typedef __attribute__((ext_vector_type(4))) float f32x4;

#define N_NODES 50000
#define N_EDGES 800000
#define DIM 128
#define QKVW 384

__device__ __forceinline__ float bfu2f(unsigned short u){
  return __uint_as_float(((unsigned)u) << 16);
}
__device__ __forceinline__ unsigned short f2bfbits(float f){
  bf16 t = __float2bfloat16(f);
  return *reinterpret_cast<unsigned short*>(&t);
}

__global__ void fill_kernel(unsigned* __restrict__ p, unsigned val, int n){
  int i = blockIdx.x * blockDim.x + threadIdx.x;
  if (i < n) p[i] = val;
}

// batched transpose+bf16: W[l][K][M] fp32 -> Wt[l][M][K] bf16
__global__ void prep_w_kernel(const float* __restrict__ W, bf16* __restrict__ Wt,
    int K, int M, int L){
  int idx = blockIdx.x * blockDim.x + threadIdx.x;
  int tot = L * K * M;
  if (idx >= tot) return;
  int l = idx / (K * M), r = idx - l * (K * M);
  int m = r / K, k = r - m * K;
  Wt[idx] = __float2bfloat16(W[(size_t)l * K * M + (size_t)k * M + m]);
}

// qkv packed layout is [q | v | k] so attn can read q and v with one base
// pointer (v at constant +256B). k sits at +512B, read once per dst.
__global__ void prep_qkvw_kernel(const float* __restrict__ Wq, const float* __restrict__ Wk,
    const float* __restrict__ Wv, bf16* __restrict__ Wt){
  int idx = blockIdx.x * blockDim.x + threadIdx.x;
  if (idx >= 5 * QKVW * 128) return;
  int l = idx / (QKVW * 128), r = idx - l * (QKVW * 128);
  int m = r / 128, k = r - m * 128;
  const float* src = (m < 128) ? (Wq + (size_t)l * 16384 + (size_t)k * 128 + m)
                   : (m < 256) ? (Wv + (size_t)l * 16384 + (size_t)k * 128 + (m - 128))
                               : (Wk + (size_t)l * 16384 + (size_t)k * 128 + (m - 256));
  Wt[idx] = __float2bfloat16(*src);
}

__global__ void pack_qkvbias_kernel(const float* __restrict__ bq, const float* __restrict__ bk,
    const float* __restrict__ bv, float* __restrict__ bqkv){
  int i = blockIdx.x * blockDim.x + threadIdx.x;
  if (i >= 5 * QKVW) return;
  int l = i / QKVW, j = i - l * QKVW;
  float v = (j < 128) ? bq[l * 128 + j] : (j < 256) ? bv[l * 128 + j - 128] : bk[l * 128 + j - 256];
  bqkv[i] = v;
}

// ---- CSR build: hist -> 3-phase parallel scan -> scatter ----
__global__ void hist_kernel(const int* __restrict__ dst, int* __restrict__ counts, int E){
  int e = blockIdx.x * blockDim.x + threadIdx.x;
  if (e < E) atomicAdd(counts + dst[e], 1);
}

__global__ __launch_bounds__(256) void blockscan_kernel(const int* __restrict__ counts,
    int* __restrict__ rowptr, int* __restrict__ bsum, int n){
  __shared__ int buf[256];
  int t = threadIdx.x, i = blockIdx.x * 256 + t;
  int x = (i < n) ? counts[i] : 0;
  buf[t] = x; __syncthreads();
  #pragma unroll
  for (int off = 1; off < 256; off <<= 1){
    int v = (t >= off) ? buf[t - off] : 0;
    __syncthreads(); buf[t] += v; __syncthreads();
  }
  if (i < n) rowptr[i] = buf[t] - x;
  if (t == 255) bsum[blockIdx.x] = buf[255];
}

__global__ __launch_bounds__(256) void scanb_kernel(int* __restrict__ bsum, int nb){
  __shared__ int buf[256];
  int t = threadIdx.x;
  int x = (t < nb) ? bsum[t] : 0;
  buf[t] = x; __syncthreads();
  #pragma unroll
  for (int off = 1; off < 256; off <<= 1){
    int v = (t >= off) ? buf[t - off] : 0;
    __syncthreads(); buf[t] += v; __syncthreads();
  }
  if (t < nb) bsum[t] = buf[t] - x;
  if (t == nb - 1) bsum[nb] = buf[t];
}

__global__ void addoff_kernel(int* __restrict__ rowptr, const int* __restrict__ bsum,
    int n, int nb){
  int i = blockIdx.x * blockDim.x + threadIdx.x;
  if (i < n) rowptr[i] += bsum[i >> 8];
  if (i == 0) rowptr[n] = bsum[nb];
}

__global__ void scatter_kernel(const int* __restrict__ src, const int* __restrict__ dst,
    const int* __restrict__ rowptr, int* __restrict__ cursor,
    int* __restrict__ srclist, int E){
  int e = blockIdx.x * blockDim.x + threadIdx.x;
  if (e >= E) return;
  int d = dst[e];
  int pos = rowptr[d] + atomicAdd(cursor + d, 1);
  srclist[pos] = src[e];
}

// ---- gather attention v2 (verified; at ~3.4 TB/s random-gather ceiling) ----
__global__ __launch_bounds__(256) void attn_kernel(
    const int* __restrict__ rowptr, const int* __restrict__ srclist,
    const bf16* __restrict__ qkv, bf16* __restrict__ agg, int n){
  int d = blockIdx.x * 4 + (threadIdx.x >> 6);
  int lane = threadIdx.x & 63;
  if (d >= n) return;
  int eslot = lane >> 4;          // 0..3 edge slot
  int t = lane & 15;              // feature slot: elems 8t..8t+7, head = t>>1
  float kf[8];
  {
    const int4* kp = (const int4*)(qkv + (size_t)d * QKVW + 256 + t * 8);
    int4 kv = kp[0];
    const unsigned* ku = (const unsigned*)&kv;
    #pragma unroll
    for (int j = 0; j < 4; j++){
      kf[2*j]   = __uint_as_float(ku[j] << 16) * 0.25f;
      kf[2*j+1] = __uint_as_float(ku[j] & 0xffff0000u) * 0.25f;
    }
  }
  float acc[8];
  #pragma unroll
  for (int j = 0; j < 8; j++) acc[j] = 0.f;
  float den = 0.f;
  int e = rowptr[d], e1 = rowptr[d + 1];
  for (; e < e1; e += 8){
    int eeA = e + eslot, eeB = e + 4 + eslot;
    int sA = srclist[(eeA < e1) ? eeA : (e1 - 1)];
    int sB = srclist[(eeB < e1) ? eeB : (e1 - 1)];
    const int4* qpA = (const int4*)(qkv + (size_t)sA * QKVW + t * 8);
    const int4* qpB = (const int4*)(qkv + (size_t)sB * QKVW + t * 8);
    int4 qA = qpA[0];
    int4 vA = qpA[16];            // +256B = v slice
    int4 qB = qpB[0];
    int4 vB = qpB[16];
    float pA = 0.f, pB = 0.f;
    const unsigned* qa = (const unsigned*)&qA;
    const unsigned* qb = (const unsigned*)&qB;
    #pragma unroll
    for (int j = 0; j < 4; j++){
      pA = fmaf(__uint_as_float(qa[j] << 16),          kf[2*j],   pA);
      pA = fmaf(__uint_as_float(qa[j] & 0xffff0000u),  kf[2*j+1], pA);
      pB = fmaf(__uint_as_float(qb[j] << 16),          kf[2*j],   pB);
      pB = fmaf(__uint_as_float(qb[j] & 0xffff0000u),  kf[2*j+1], pB);
    }
    pA += __shfl_xor(pA, 1);      // head-pair reduce (head spans 2 lanes)
    pB += __shfl_xor(pB, 1);
    float wA = (eeA < e1) ? __expf(pA) : 0.f;
    float wB = (eeB < e1) ? __expf(pB) : 0.f;
    den += wA + wB;
    const unsigned* va = (const unsigned*)&vA;
    const unsigned* vb = (const unsigned*)&vB;
    #pragma unroll
    for (int j = 0; j < 4; j++){
      acc[2*j]   = fmaf(wA, __uint_as_float(va[j] << 16),         acc[2*j]);
      acc[2*j+1] = fmaf(wA, __uint_as_float(va[j] & 0xffff0000u), acc[2*j+1]);
      acc[2*j]   = fmaf(wB, __uint_as_float(vb[j] << 16),         acc[2*j]);
      acc[2*j+1] = fmaf(wB, __uint_as_float(vb[j] & 0xffff0000u), acc[2*j+1]);
    }
  }
  #pragma unroll
  for (int m = 16; m <= 32; m <<= 1){
    den += __shfl_xor(den, m);
    #pragma unroll
    for (int j = 0; j < 8; j++) acc[j] += __shfl_xor(acc[j], m);
  }
  if (eslot == 0){
    float inv = (den > 0.f) ? 1.f / den : 0.f;
    unsigned short o[8];
    #pragma unroll
    for (int j = 0; j < 8; j++) o[j] = f2bfbits(acc[j] * inv);
    *(int4*)(agg + (size_t)d * DIM + t * 8) = *(const int4*)o;
  }
}

// ---- MFMA GEMM v6: v5 (swapped-operand vector epilogue) + bf16 h stream.
// A can be f32 or bf16, both with optional fused LN; resid typed as OT
// (bf16 h residuals load as int2 of 4 bf16). Math per element unchanged
// except h is stored/reloaded in bf16.
template<int KT, int MT, typename AT, bool FUSELN, bool RELU, bool RESID, typename OT>
__global__ __launch_bounds__(256, (KT == 128) ? 4 : 2) void pgemm4(
    const AT* __restrict__ A, const float* __restrict__ lng, const float* __restrict__ lnb,
    const bf16* __restrict__ Wt, const float* __restrict__ bias,
    const OT* __restrict__ resid, OT* __restrict__ out, float* __restrict__ out2,
    int n, int M){
  constexpr int CPR = KT / 8;              // 16B chunks per A row
  constexpr int CPT = (64 * CPR) / 256;    // chunks per thread
  constexpr int NMT = MT / 64;             // col-tiles
  constexpr int NKS = KT / 32;             // k-steps
  __shared__ short Ash[64][KT + 8];
  int tid = threadIdx.x;
  int wv = tid >> 6, lane = tid & 63;
  int l15 = lane & 15, quad = lane >> 4;
  int bm = blockIdx.x * 64;

  bf16x8 wf[2][NKS];
  auto loadW = [&](int mt, int b){
    int col = mt * 64 + wv * 16 + l15;
    #pragma unroll
    for (int ks = 0; ks < NKS; ks++){
      int4 w = make_int4(0, 0, 0, 0);
      if (col < M) w = *(const int4*)(Wt + (size_t)col * KT + ks * 32 + quad * 8);
      wf[b][ks] = *(bf16x8*)&w;
    }
  };
  loadW(0, 0);   // prefetch first col-tile during A staging

  // stage A row-block (optional fused LN; f32 input converts to bf16)
  #pragma unroll
  for (int i = 0; i < CPT; i++){
    int c = tid + i * 256;
    int row = c / CPR, off = (c - row * CPR) * 8;
    int gr = bm + row;
    float va[8];
    bool have = false;
    if constexpr (sizeof(AT) == 4){
      if (gr < n){
        float4 f0 = *(const float4*)(A + (size_t)gr * KT + off);
        float4 f1 = *(const float4*)(A + (size_t)gr * KT + off + 4);
        va[0]=f0.x; va[1]=f0.y; va[2]=f0.z; va[3]=f0.w;
        va[4]=f1.x; va[5]=f1.y; va[6]=f1.z; va[7]=f1.w;
      } else {
        #pragma unroll
        for (int j = 0; j < 8; j++) va[j] = 0.f;
      }
      have = true;
    } else {
      int4 av = make_int4(0, 0, 0, 0);
      if (gr < n) av = *(const int4*)(A + (size_t)gr * KT + off);
      if constexpr (FUSELN){
        const unsigned short* u = (const unsigned short*)&av;
        #pragma unroll
        for (int j = 0; j < 8; j++) va[j] = bfu2f(u[j]);
        have = true;
      } else {
        *(int4*)(&Ash[row][off]) = av;
      }
    }
    if (have){
      if constexpr (FUSELN){  // KT==128: 16 consecutive lanes own one row
        float s = va[0]+va[1]+va[2]+va[3]+va[4]+va[5]+va[6]+va[7];
        s += __shfl_xor(s, 1); s += __shfl_xor(s, 2);
        s += __shfl_xor(s, 4); s += __shfl_xor(s, 8);
        float mu = s * (1.f / 128.f);
        float vs = 0.f;
        #pragma unroll
        for (int j = 0; j < 8; j++){ float dd = va[j] - mu; vs += dd * dd; }
        vs += __shfl_xor(vs, 1); vs += __shfl_xor(vs, 2);
        vs += __shfl_xor(vs, 4); vs += __shfl_xor(vs, 8);
        float rs = rsqrtf(vs * (1.f / 128.f) + 1e-5f);
        float4 g0 = *(const float4*)(lng + off);
        float4 g1 = *(const float4*)(lng + off + 4);
        float4 b0 = *(const float4*)(lnb + off);
        float4 b1 = *(const float4*)(lnb + off + 4);
        va[0]=(va[0]-mu)*rs*g0.x+b0.x; va[1]=(va[1]-mu)*rs*g0.y+b0.y;
        va[2]=(va[2]-mu)*rs*g0.z+b0.z; va[3]=(va[3]-mu)*rs*g0.w+b0.w;
        va[4]=(va[4]-mu)*rs*g1.x+b1.x; va[5]=(va[5]-mu)*rs*g1.y+b1.y;
        va[6]=(va[6]-mu)*rs*g1.z+b1.z; va[7]=(va[7]-mu)*rs*g1.w+b1.w;
      }
      unsigned short tmp[8];
      #pragma unroll
      for (int j = 0; j < 8; j++) tmp[j] = f2bfbits(va[j]);
      *(int4*)(&Ash[row][off]) = *(const int4*)tmp;
    }
  }
  __syncthreads();

  #pragma unroll
  for (int mt = 0; mt < NMT; mt++){
    int b = mt & 1;
    if (mt + 1 < NMT) loadW(mt + 1, b ^ 1);   // prefetch next tile's W
    f32x4 acc[4];
    #pragma unroll
    for (int i = 0; i < 4; i++) acc[i] = (f32x4){0.f, 0.f, 0.f, 0.f};
    #pragma unroll
    for (int ks = 0; ks < NKS; ks++){
      bf16x8 bfrag = wf[b][ks];
      #pragma unroll
      for (int rt = 0; rt < 4; rt++){
        bf16x8 afrag = *(const bf16x8*)(&Ash[rt * 16 + l15][ks * 32 + quad * 8]);
        // SWAPPED operands: lane owns row=bm+rt*16+l15, cols=colb..colb+3.
        acc[rt] = __builtin_amdgcn_mfma_f32_16x16x32_bf16(bfrag, afrag, acc[rt], 0, 0, 0);
      }
    }
    int colb = mt * 64 + wv * 16 + quad * 4;   // base col of this lane's 4 regs
    if (colb < M){
      float4 bv4 = *(const float4*)(bias + colb);
      #pragma unroll
      for (int rt = 0; rt < 4; rt++){
        int grow = bm + rt * 16 + l15;
        if (grow >= n) continue;
        float4 v;
        v.x = acc[rt][0] + bv4.x; v.y = acc[rt][1] + bv4.y;
        v.z = acc[rt][2] + bv4.z; v.w = acc[rt][3] + bv4.w;
        if (RELU){
          v.x = fmaxf(v.x, 0.f); v.y = fmaxf(v.y, 0.f);
          v.z = fmaxf(v.z, 0.f); v.w = fmaxf(v.w, 0.f);
        }
        if (RESID){
          if constexpr (sizeof(OT) == 4){
            float4 r = *(const float4*)((const float*)resid + (size_t)grow * M + colb);
            v.x += r.x; v.y += r.y; v.z += r.z; v.w += r.w;
          } else {
            int2 r2 = *(const int2*)((const bf16*)resid + (size_t)grow * M + colb);
            const unsigned short* ru = (const unsigned short*)&r2;
            v.x += bfu2f(ru[0]); v.y += bfu2f(ru[1]);
            v.z += bfu2f(ru[2]); v.w += bfu2f(ru[3]);
          }
        }
        if constexpr (sizeof(OT) == 4){
          *(float4*)((float*)out + (size_t)grow * M + colb) = v;
        } else {
          unsigned short o[4];
          o[0] = f2bfbits(v.x); o[1] = f2bfbits(v.y);
          o[2] = f2bfbits(v.z); o[3] = f2bfbits(v.w);
          *(int2*)((bf16*)out + (size_t)grow * M + colb) = *(const int2*)o;
        }
        if (out2) *(float4*)(out2 + (size_t)grow * M + colb) = v;
      }
    }
  }
}

extern "C" void kernel_launch(void* const* d_in, const int* in_sizes, int n_in,
                              void* d_out, int out_size, void* d_ws, size_t ws_size,
                              hipStream_t stream) {
  const float* x    = (const float*)d_in[0];
  const int*  esrc  = (const int*)d_in[1];
  const int*  edst  = (const int*)d_in[2];
  const float* Wi   = (const float*)d_in[3];
  const float* bi   = (const float*)d_in[4];
  const float* Wq   = (const float*)d_in[5];
  const float* bq   = (const float*)d_in[6];
  const float* Wk   = (const float*)d_in[7];
  const float* bk   = (const float*)d_in[8];
  const float* Wv   = (const float*)d_in[9];
  const float* bv   = (const float*)d_in[10];
  const float* Wo   = (const float*)d_in[11];
  const float* bo   = (const float*)d_in[12];
  const float* g1   = (const float*)d_in[13];
  const float* b1   = (const float*)d_in[14];
  const float* Wf1  = (const float*)d_in[15];
  const float* bf1  = (const float*)d_in[16];
  const float* Wf2  = (const float*)d_in[17];
  const float* bf2  = (const float*)d_in[18];
  const float* gout = (const float*)d_in[19];
  const float* bout_ln = (const float*)d_in[20];
  const float* Wout = (const float*)d_in[21];
  const float* bout = (const float*)d_in[22];

  const size_t ND = (size_t)N_NODES * DIM;   // 6.4M elems
  float* ws = (float*)d_ws;
  bf16* hb   = (bf16*)ws;                     // N*128 bf16
  bf16* agg  = hb + ND;                       // N*128 bf16
  bf16* qkv  = agg + ND;                      // N*384 bf16
  bf16* mid  = qkv;                           // overlay [N,256] bf16
  bf16* Wit    = qkv + (size_t)N_NODES * QKVW;       // 128*256
  bf16* Wqkvt  = Wit + 128 * 256;                    // 5*384*128
  bf16* Wot    = Wqkvt + 5 * QKVW * 128;             // 5*128*128
  bf16* Wf1t   = Wot + 5 * 128 * 128;                // 5*256*128
  bf16* Wf2t   = Wf1t + 5 * 256 * 128;               // 5*128*256
  bf16* Woutt  = Wf2t + 5 * 128 * 256;               // 40*128
  float* bqkv  = (float*)(Woutt + 40 * 128);         // 5*384 f32
  int* rowptr  = (int*)(bqkv + 5 * QKVW);            // N+1
  int* cnt     = rowptr + N_NODES + 1;               // N
  int* bsum    = cnt + N_NODES;                      // 197
  int* srclist = bsum + 200;                         // E

  dim3 B(256);
  const int EB = (N_EDGES + 255) / 256;
  const int NB = (N_NODES + 255) / 256;
  const int NSB = (N_NODES + 255) / 256;             // 196 scan blocks
  dim3 Grow(782);

  // ---- prep ----
  prep_w_kernel<<<(1 * 256 * 128 + 255) / 256, B, 0, stream>>>(Wi, Wit, 256, 128, 1);
  prep_qkvw_kernel<<<(5 * QKVW * 128 + 255) / 256, B, 0, stream>>>(Wq, Wk, Wv, Wqkvt);
  prep_w_kernel<<<(5 * 128 * 128 + 255) / 256, B, 0, stream>>>(Wo, Wot, 128, 128, 5);
  prep_w_kernel<<<(5 * 128 * 256 + 255) / 256, B, 0, stream>>>(Wf1, Wf1t, 128, 256, 5);
  prep_w_kernel<<<(5 * 256 * 128 + 255) / 256, B, 0, stream>>>(Wf2, Wf2t, 256, 128, 5);
  prep_w_kernel<<<(1 * 128 * 40 + 255) / 256, B, 0, stream>>>(Wout, Woutt, 128, 40, 1);
  pack_qkvbias_kernel<<<(5 * QKVW + 255) / 256, B, 0, stream>>>(bq, bk, bv, bqkv);
  fill_kernel<<<NB, B, 0, stream>>>((unsigned*)cnt, 0u, N_NODES);
  hist_kernel<<<EB, B, 0, stream>>>(edst, cnt, N_EDGES);
  blockscan_kernel<<<NSB, B, 0, stream>>>(cnt, rowptr, bsum, N_NODES);
  scanb_kernel<<<1, B, 0, stream>>>(bsum, NSB);
  addoff_kernel<<<NB, B, 0, stream>>>(rowptr, bsum, N_NODES, NSB);
  fill_kernel<<<NB, B, 0, stream>>>((unsigned*)cnt, 0u, N_NODES);
  scatter_kernel<<<EB, B, 0, stream>>>(esrc, edst, rowptr, cnt, srclist, N_EDGES);

  // h = relu(x @ Wi + bi)  (h now bf16)
  pgemm4<256, 128, float, false, true, false, bf16><<<Grow, B, 0, stream>>>(
      x, nullptr, nullptr, Wit, bi, nullptr, hb, nullptr, N_NODES, 128);

  for (int l = 0; l < 5; l++){
    // qkv = LN(h) @ [Wq|Wv|Wk] + bias  (LN fused, bf16 A)
    pgemm4<128, 384, bf16, true, false, false, bf16><<<Grow, B, 0, stream>>>(
        hb, g1 + l * DIM, b1 + l * DIM, Wqkvt + (size_t)l * QKVW * 128,
        bqkv + l * QKVW, nullptr, qkv, nullptr, N_NODES, QKVW);
    attn_kernel<<<12500, B, 0, stream>>>(rowptr, srclist, qkv, agg, N_NODES);
    // h = h + agg @ Wo + bo
    pgemm4<128, 128, bf16, false, false, true, bf16><<<Grow, B, 0, stream>>>(
        agg, nullptr, nullptr, Wot + (size_t)l * 128 * 128, bo + l * DIM,
        hb, hb, nullptr, N_NODES, 128);
    // mid = relu(LN(h) @ Wf1 + bf1)  (reference reuses g1/b1)
    pgemm4<128, 256, bf16, true, true, false, bf16><<<Grow, B, 0, stream>>>(
        hb, g1 + l * DIM, b1 + l * DIM, Wf1t + (size_t)l * 256 * 128,
        bf1 + l * 2 * DIM, nullptr, mid, nullptr, N_NODES, 256);
    // h = h + mid @ Wf2 + bf2 ; last layer dual-writes d_out (mid, f32 pre-round)
    float* out2 = (l == 4) ? (float*)d_out : nullptr;
    pgemm4<256, 128, bf16, false, false, true, bf16><<<Grow, B, 0, stream>>>(
        mid, nullptr, nullptr, Wf2t + (size_t)l * 128 * 256, bf2 + l * DIM,
        hb, hb, out2, N_NODES, 128);
  }

  // out = LN(h, g_out, b_out) @ Wout + bout  (M=40)
  pgemm4<128, 64, bf16, true, false, false, float><<<Grow, B, 0, stream>>>(
      hb, gout, bout_ln, Woutt, bout, nullptr, ((float*)d_out) + ND, nullptr, N_NODES, 40);
}

// Round 6
// 889.514 us; speedup vs baseline: 1.4032x; 1.0542x over previous
//
#include <hip/hip_runtime.h>
#include <hip/hip_bf16.h>

typedef __hip_bfloat16 bf16;
typedef __attribute__((ext_vector_type(8))) short bf16x8;
typedef __attribute__((ext_vector_type(4))) float f32x4;

#define N_NODES 50000
#define N_EDGES 800000
#define DIM 128
#define QKVW 384

__device__ __forceinline__ float bfu2f(unsigned short u){
  return __uint_as_float(((unsigned)u) << 16);
}
__device__ __forceinline__ unsigned short f2bfbits(float f){
  bf16 t = __float2bfloat16(f);
  return *reinterpret_cast<unsigned short*>(&t);
}

__global__ void fill_kernel(unsigned* __restrict__ p, unsigned val, int n){
  int i = blockIdx.x * blockDim.x + threadIdx.x;
  if (i < n) p[i] = val;
}

// ---- single merged prep kernel: all weight transposes (fp32->bf16, [l][m][k])
// plus qkv bias pack, over a partitioned flat index space.
// Region order: Wit(32768) Wqkvt(245760) Wot(81920) Wf1t(163840) Wf2t(163840)
// Woutt(5120) bqkv(1920)  => total 695168.
__global__ void prep_all_kernel(
    const float* __restrict__ Wi, const float* __restrict__ Wq,
    const float* __restrict__ Wk, const float* __restrict__ Wv,
    const float* __restrict__ Wo, const float* __restrict__ Wf1,
    const float* __restrict__ Wf2, const float* __restrict__ Wout,
    const float* __restrict__ bq, const float* __restrict__ bk,
    const float* __restrict__ bv,
    bf16* __restrict__ Wit, bf16* __restrict__ Wqkvt, bf16* __restrict__ Wot,
    bf16* __restrict__ Wf1t, bf16* __restrict__ Wf2t, bf16* __restrict__ Woutt,
    float* __restrict__ bqkv){
  int idx = blockIdx.x * blockDim.x + threadIdx.x;
  if (idx < 32768){                       // Wit: K=256, M=128
    int m = idx >> 8, k = idx & 255;
    Wit[idx] = __float2bfloat16(Wi[k * 128 + m]);
    return;
  }
  idx -= 32768;
  if (idx < 245760){                      // Wqkvt: [q|v|k] pack, K=128, M=384
    int l = idx / (384 * 128), r = idx - l * (384 * 128);
    int m = r >> 7, k = r & 127;
    const float* src = (m < 128) ? (Wq + (size_t)l * 16384 + (size_t)k * 128 + m)
                     : (m < 256) ? (Wv + (size_t)l * 16384 + (size_t)k * 128 + (m - 128))
                                 : (Wk + (size_t)l * 16384 + (size_t)k * 128 + (m - 256));
    Wqkvt[idx] = __float2bfloat16(*src);
    return;
  }
  idx -= 245760;
  if (idx < 81920){                       // Wot: K=128, M=128
    int l = idx >> 14, r = idx & 16383;
    int m = r >> 7, k = r & 127;
    Wot[idx] = __float2bfloat16(Wo[(size_t)l * 16384 + (size_t)k * 128 + m]);
    return;
  }
  idx -= 81920;
  if (idx < 163840){                      // Wf1t: K=128, M=256
    int l = idx >> 15, r = idx & 32767;
    int m = r >> 7, k = r & 127;
    Wf1t[idx] = __float2bfloat16(Wf1[(size_t)l * 32768 + (size_t)k * 256 + m]);
    return;
  }
  idx -= 163840;
  if (idx < 163840){                      // Wf2t: K=256, M=128
    int l = idx >> 15, r = idx & 32767;
    int m = r >> 8, k = r & 255;
    Wf2t[idx] = __float2bfloat16(Wf2[(size_t)l * 32768 + (size_t)k * 128 + m]);
    return;
  }
  idx -= 163840;
  if (idx < 5120){                        // Woutt: K=128, M=40
    int m = idx >> 7, k = idx & 127;
    Woutt[idx] = __float2bfloat16(Wout[k * 40 + m]);
    return;
  }
  idx -= 5120;
  if (idx < 1920){                        // bqkv pack [q|v|k]
    int l = idx / 384, j = idx - l * 384;
    float v = (j < 128) ? bq[l * 128 + j] : (j < 256) ? bv[l * 128 + j - 128]
                                                      : bk[l * 128 + j - 256];
    bqkv[idx] = v;
  }
}

// ---- CSR build v2: hist persists within-row index (atomic return) -> scatter
// needs NO atomic (pure fire-and-forget store, full MLP). ----
__global__ void hist_kernel(const int* __restrict__ dst, int* __restrict__ counts,
    int* __restrict__ tmp, int E){
  int e = blockIdx.x * blockDim.x + threadIdx.x;
  if (e < E) tmp[e] = atomicAdd(counts + dst[e], 1);
}

__global__ __launch_bounds__(256) void blockscan_kernel(const int* __restrict__ counts,
    int* __restrict__ rowptr, int* __restrict__ bsum, int n){
  __shared__ int buf[256];
  int t = threadIdx.x, i = blockIdx.x * 256 + t;
  int x = (i < n) ? counts[i] : 0;
  buf[t] = x; __syncthreads();
  #pragma unroll
  for (int off = 1; off < 256; off <<= 1){
    int v = (t >= off) ? buf[t - off] : 0;
    __syncthreads(); buf[t] += v; __syncthreads();
  }
  if (i < n) rowptr[i] = buf[t] - x;
  if (t == 255) bsum[blockIdx.x] = buf[255];
}

__global__ __launch_bounds__(256) void scanb_kernel(int* __restrict__ bsum, int nb){
  __shared__ int buf[256];
  int t = threadIdx.x;
  int x = (t < nb) ? bsum[t] : 0;
  buf[t] = x; __syncthreads();
  #pragma unroll
  for (int off = 1; off < 256; off <<= 1){
    int v = (t >= off) ? buf[t - off] : 0;
    __syncthreads(); buf[t] += v; __syncthreads();
  }
  if (t < nb) bsum[t] = buf[t] - x;
  if (t == nb - 1) bsum[nb] = buf[t];
}

__global__ void addoff_kernel(int* __restrict__ rowptr, const int* __restrict__ bsum,
    int n, int nb){
  int i = blockIdx.x * blockDim.x + threadIdx.x;
  if (i < n) rowptr[i] += bsum[i >> 8];
  if (i == 0) rowptr[n] = bsum[nb];
}

__global__ void scatter_kernel(const int* __restrict__ src, const int* __restrict__ dst,
    const int* __restrict__ rowptr, const int* __restrict__ tmp,
    int* __restrict__ srclist, int E){
  int e = blockIdx.x * blockDim.x + threadIdx.x;
  if (e >= E) return;
  srclist[rowptr[dst[e]] + tmp[e]] = src[e];
}

// ---- gather attention v2 (verified; at ~3.5 TB/s random-gather ceiling) ----
__global__ __launch_bounds__(256) void attn_kernel(
    const int* __restrict__ rowptr, const int* __restrict__ srclist,
    const bf16* __restrict__ qkv, bf16* __restrict__ agg, int n){
  int d = blockIdx.x * 4 + (threadIdx.x >> 6);
  int lane = threadIdx.x & 63;
  if (d >= n) return;
  int eslot = lane >> 4;          // 0..3 edge slot
  int t = lane & 15;              // feature slot: elems 8t..8t+7, head = t>>1
  float kf[8];
  {
    const int4* kp = (const int4*)(qkv + (size_t)d * QKVW + 256 + t * 8);
    int4 kv = kp[0];
    const unsigned* ku = (const unsigned*)&kv;
    #pragma unroll
    for (int j = 0; j < 4; j++){
      kf[2*j]   = __uint_as_float(ku[j] << 16) * 0.25f;
      kf[2*j+1] = __uint_as_float(ku[j] & 0xffff0000u) * 0.25f;
    }
  }
  float acc[8];
  #pragma unroll
  for (int j = 0; j < 8; j++) acc[j] = 0.f;
  float den = 0.f;
  int e = rowptr[d], e1 = rowptr[d + 1];
  for (; e < e1; e += 8){
    int eeA = e + eslot, eeB = e + 4 + eslot;
    int sA = srclist[(eeA < e1) ? eeA : (e1 - 1)];
    int sB = srclist[(eeB < e1) ? eeB : (e1 - 1)];
    const int4* qpA = (const int4*)(qkv + (size_t)sA * QKVW + t * 8);
    const int4* qpB = (const int4*)(qkv + (size_t)sB * QKVW + t * 8);
    int4 qA = qpA[0];
    int4 vA = qpA[16];            // +256B = v slice
    int4 qB = qpB[0];
    int4 vB = qpB[16];
    float pA = 0.f, pB = 0.f;
    const unsigned* qa = (const unsigned*)&qA;
    const unsigned* qb = (const unsigned*)&qB;
    #pragma unroll
    for (int j = 0; j < 4; j++){
      pA = fmaf(__uint_as_float(qa[j] << 16),          kf[2*j],   pA);
      pA = fmaf(__uint_as_float(qa[j] & 0xffff0000u),  kf[2*j+1], pA);
      pB = fmaf(__uint_as_float(qb[j] << 16),          kf[2*j],   pB);
      pB = fmaf(__uint_as_float(qb[j] & 0xffff0000u),  kf[2*j+1], pB);
    }
    pA += __shfl_xor(pA, 1);      // head-pair reduce (head spans 2 lanes)
    pB += __shfl_xor(pB, 1);
    float wA = (eeA < e1) ? __expf(pA) : 0.f;
    float wB = (eeB < e1) ? __expf(pB) : 0.f;
    den += wA + wB;
    const unsigned* va = (const unsigned*)&vA;
    const unsigned* vb = (const unsigned*)&vB;
    #pragma unroll
    for (int j = 0; j < 4; j++){
      acc[2*j]   = fmaf(wA, __uint_as_float(va[j] << 16),         acc[2*j]);
      acc[2*j+1] = fmaf(wA, __uint_as_float(va[j] & 0xffff0000u), acc[2*j+1]);
      acc[2*j]   = fmaf(wB, __uint_as_float(vb[j] << 16),         acc[2*j]);
      acc[2*j+1] = fmaf(wB, __uint_as_float(vb[j] & 0xffff0000u), acc[2*j+1]);
    }
  }
  #pragma unroll
  for (int m = 16; m <= 32; m <<= 1){
    den += __shfl_xor(den, m);
    #pragma unroll
    for (int j = 0; j < 8; j++) acc[j] += __shfl_xor(acc[j], m);
  }
  if (eslot == 0){
    float inv = (den > 0.f) ? 1.f / den : 0.f;
    unsigned short o[8];
    #pragma unroll
    for (int j = 0; j < 8; j++) o[j] = f2bfbits(acc[j] * inv);
    *(int4*)(agg + (size_t)d * DIM + t * 8) = *(const int4*)o;
  }
}

// ---- MFMA GEMM v6: swapped-operand vector epilogue + bf16 h stream. ----
template<int KT, int MT, typename AT, bool FUSELN, bool RELU, bool RESID, typename OT>
__global__ __launch_bounds__(256, (KT == 128) ? 4 : 2) void pgemm4(
    const AT* __restrict__ A, const float* __restrict__ lng, const float* __restrict__ lnb,
    const bf16* __restrict__ Wt, const float* __restrict__ bias,
    const OT* __restrict__ resid, OT* __restrict__ out, float* __restrict__ out2,
    int n, int M){
  constexpr int CPR = KT / 8;              // 16B chunks per A row
  constexpr int CPT = (64 * CPR) / 256;    // chunks per thread
  constexpr int NMT = MT / 64;             // col-tiles
  constexpr int NKS = KT / 32;             // k-steps
  __shared__ short Ash[64][KT + 8];
  int tid = threadIdx.x;
  int wv = tid >> 6, lane = tid & 63;
  int l15 = lane & 15, quad = lane >> 4;
  int bm = blockIdx.x * 64;

  bf16x8 wf[2][NKS];
  auto loadW = [&](int mt, int b){
    int col = mt * 64 + wv * 16 + l15;
    #pragma unroll
    for (int ks = 0; ks < NKS; ks++){
      int4 w = make_int4(0, 0, 0, 0);
      if (col < M) w = *(const int4*)(Wt + (size_t)col * KT + ks * 32 + quad * 8);
      wf[b][ks] = *(bf16x8*)&w;
    }
  };
  loadW(0, 0);   // prefetch first col-tile during A staging

  // stage A row-block (optional fused LN; f32 input converts to bf16)
  #pragma unroll
  for (int i = 0; i < CPT; i++){
    int c = tid + i * 256;
    int row = c / CPR, off = (c - row * CPR) * 8;
    int gr = bm + row;
    float va[8];
    bool have = false;
    if constexpr (sizeof(AT) == 4){
      if (gr < n){
        float4 f0 = *(const float4*)(A + (size_t)gr * KT + off);
        float4 f1 = *(const float4*)(A + (size_t)gr * KT + off + 4);
        va[0]=f0.x; va[1]=f0.y; va[2]=f0.z; va[3]=f0.w;
        va[4]=f1.x; va[5]=f1.y; va[6]=f1.z; va[7]=f1.w;
      } else {
        #pragma unroll
        for (int j = 0; j < 8; j++) va[j] = 0.f;
      }
      have = true;
    } else {
      int4 av = make_int4(0, 0, 0, 0);
      if (gr < n) av = *(const int4*)(A + (size_t)gr * KT + off);
      if constexpr (FUSELN){
        const unsigned short* u = (const unsigned short*)&av;
        #pragma unroll
        for (int j = 0; j < 8; j++) va[j] = bfu2f(u[j]);
        have = true;
      } else {
        *(int4*)(&Ash[row][off]) = av;
      }
    }
    if (have){
      if constexpr (FUSELN){  // KT==128: 16 consecutive lanes own one row
        float s = va[0]+va[1]+va[2]+va[3]+va[4]+va[5]+va[6]+va[7];
        s += __shfl_xor(s, 1); s += __shfl_xor(s, 2);
        s += __shfl_xor(s, 4); s += __shfl_xor(s, 8);
        float mu = s * (1.f / 128.f);
        float vs = 0.f;
        #pragma unroll
        for (int j = 0; j < 8; j++){ float dd = va[j] - mu; vs += dd * dd; }
        vs += __shfl_xor(vs, 1); vs += __shfl_xor(vs, 2);
        vs += __shfl_xor(vs, 4); vs += __shfl_xor(vs, 8);
        float rs = rsqrtf(vs * (1.f / 128.f) + 1e-5f);
        float4 g0 = *(const float4*)(lng + off);
        float4 g1 = *(const float4*)(lng + off + 4);
        float4 b0 = *(const float4*)(lnb + off);
        float4 b1 = *(const float4*)(lnb + off + 4);
        va[0]=(va[0]-mu)*rs*g0.x+b0.x; va[1]=(va[1]-mu)*rs*g0.y+b0.y;
        va[2]=(va[2]-mu)*rs*g0.z+b0.z; va[3]=(va[3]-mu)*rs*g0.w+b0.w;
        va[4]=(va[4]-mu)*rs*g1.x+b1.x; va[5]=(va[5]-mu)*rs*g1.y+b1.y;
        va[6]=(va[6]-mu)*rs*g1.z+b1.z; va[7]=(va[7]-mu)*rs*g1.w+b1.w;
      }
      unsigned short tmp[8];
      #pragma unroll
      for (int j = 0; j < 8; j++) tmp[j] = f2bfbits(va[j]);
      *(int4*)(&Ash[row][off]) = *(const int4*)tmp;
    }
  }
  __syncthreads();

  #pragma unroll
  for (int mt = 0; mt < NMT; mt++){
    int b = mt & 1;
    if (mt + 1 < NMT) loadW(mt + 1, b ^ 1);   // prefetch next tile's W
    f32x4 acc[4];
    #pragma unroll
    for (int i = 0; i < 4; i++) acc[i] = (f32x4){0.f, 0.f, 0.f, 0.f};
    #pragma unroll
    for (int ks = 0; ks < NKS; ks++){
      bf16x8 bfrag = wf[b][ks];
      #pragma unroll
      for (int rt = 0; rt < 4; rt++){
        bf16x8 afrag = *(const bf16x8*)(&Ash[rt * 16 + l15][ks * 32 + quad * 8]);
        // SWAPPED operands: lane owns row=bm+rt*16+l15, cols=colb..colb+3.
        acc[rt] = __builtin_amdgcn_mfma_f32_16x16x32_bf16(bfrag, afrag, acc[rt], 0, 0, 0);
      }
    }
    int colb = mt * 64 + wv * 16 + quad * 4;   // base col of this lane's 4 regs
    if (colb < M){
      float4 bv4 = *(const float4*)(bias + colb);
      #pragma unroll
      for (int rt = 0; rt < 4; rt++){
        int grow = bm + rt * 16 + l15;
        if (grow >= n) continue;
        float4 v;
        v.x = acc[rt][0] + bv4.x; v.y = acc[rt][1] + bv4.y;
        v.z = acc[rt][2] + bv4.z; v.w = acc[rt][3] + bv4.w;
        if (RELU){
          v.x = fmaxf(v.x, 0.f); v.y = fmaxf(v.y, 0.f);
          v.z = fmaxf(v.z, 0.f); v.w = fmaxf(v.w, 0.f);
        }
        if (RESID){
          if constexpr (sizeof(OT) == 4){
            float4 r = *(const float4*)((const float*)resid + (size_t)grow * M + colb);
            v.x += r.x; v.y += r.y; v.z += r.z; v.w += r.w;
          } else {
            int2 r2 = *(const int2*)((const bf16*)resid + (size_t)grow * M + colb);
            const unsigned short* ru = (const unsigned short*)&r2;
            v.x += bfu2f(ru[0]); v.y += bfu2f(ru[1]);
            v.z += bfu2f(ru[2]); v.w += bfu2f(ru[3]);
          }
        }
        if constexpr (sizeof(OT) == 4){
          *(float4*)((float*)out + (size_t)grow * M + colb) = v;
        } else {
          unsigned short o[4];
          o[0] = f2bfbits(v.x); o[1] = f2bfbits(v.y);
          o[2] = f2bfbits(v.z); o[3] = f2bfbits(v.w);
          *(int2*)((bf16*)out + (size_t)grow * M + colb) = *(const int2*)o;
        }
        if (out2) *(float4*)(out2 + (size_t)grow * M + colb) = v;
      }
    }
  }
}

extern "C" void kernel_launch(void* const* d_in, const int* in_sizes, int n_in,
                              void* d_out, int out_size, void* d_ws, size_t ws_size,
                              hipStream_t stream) {
  const float* x    = (const float*)d_in[0];
  const int*  esrc  = (const int*)d_in[1];
  const int*  edst  = (const int*)d_in[2];
  const float* Wi   = (const float*)d_in[3];
  const float* bi   = (const float*)d_in[4];
  const float* Wq   = (const float*)d_in[5];
  const float* bq   = (const float*)d_in[6];
  const float* Wk   = (const float*)d_in[7];
  const float* bk   = (const float*)d_in[8];
  const float* Wv   = (const float*)d_in[9];
  const float* bv   = (const float*)d_in[10];
  const float* Wo   = (const float*)d_in[11];
  const float* bo   = (const float*)d_in[12];
  const float* g1   = (const float*)d_in[13];
  const float* b1   = (const float*)d_in[14];
  const float* Wf1  = (const float*)d_in[15];
  const float* bf1  = (const float*)d_in[16];
  const float* Wf2  = (const float*)d_in[17];
  const float* bf2  = (const float*)d_in[18];
  const float* gout = (const float*)d_in[19];
  const float* bout_ln = (const float*)d_in[20];
  const float* Wout = (const float*)d_in[21];
  const float* bout = (const float*)d_in[22];

  const size_t ND = (size_t)N_NODES * DIM;   // 6.4M elems
  float* ws = (float*)d_ws;
  bf16* hb   = (bf16*)ws;                     // N*128 bf16
  bf16* agg  = hb + ND;                       // N*128 bf16
  bf16* qkv  = agg + ND;                      // N*384 bf16
  bf16* mid  = qkv;                           // overlay [N,256] bf16
  bf16* Wit    = qkv + (size_t)N_NODES * QKVW;       // 128*256
  bf16* Wqkvt  = Wit + 128 * 256;                    // 5*384*128
  bf16* Wot    = Wqkvt + 5 * QKVW * 128;             // 5*128*128
  bf16* Wf1t   = Wot + 5 * 128 * 128;                // 5*256*128
  bf16* Wf2t   = Wf1t + 5 * 256 * 128;               // 5*128*256
  bf16* Woutt  = Wf2t + 5 * 128 * 256;               // 40*128
  float* bqkv  = (float*)(Woutt + 40 * 128);         // 5*384 f32
  int* rowptr  = (int*)(bqkv + 5 * QKVW);            // N+1
  int* cnt     = rowptr + N_NODES + 1;               // N
  int* bsum    = cnt + N_NODES;                      // 197+pad
  int* srclist = bsum + 200;                         // E
  int* tmpidx  = srclist + N_EDGES;                  // E

  dim3 B(256);
  const int EB = (N_EDGES + 255) / 256;
  const int NB = (N_NODES + 255) / 256;
  const int NSB = (N_NODES + 255) / 256;             // 196 scan blocks
  dim3 Grow(782);

  // ---- prep (one merged kernel) + CSR ----
  prep_all_kernel<<<(695168 + 255) / 256, B, 0, stream>>>(
      Wi, Wq, Wk, Wv, Wo, Wf1, Wf2, Wout, bq, bk, bv,
      Wit, Wqkvt, Wot, Wf1t, Wf2t, Woutt, bqkv);
  fill_kernel<<<NB, B, 0, stream>>>((unsigned*)cnt, 0u, N_NODES);
  hist_kernel<<<EB, B, 0, stream>>>(edst, cnt, tmpidx, N_EDGES);
  blockscan_kernel<<<NSB, B, 0, stream>>>(cnt, rowptr, bsum, N_NODES);
  scanb_kernel<<<1, B, 0, stream>>>(bsum, NSB);
  addoff_kernel<<<NB, B, 0, stream>>>(rowptr, bsum, N_NODES, NSB);
  scatter_kernel<<<EB, B, 0, stream>>>(esrc, edst, rowptr, tmpidx, srclist, N_EDGES);

  // h = relu(x @ Wi + bi)  (h bf16)
  pgemm4<256, 128, float, false, true, false, bf16><<<Grow, B, 0, stream>>>(
      x, nullptr, nullptr, Wit, bi, nullptr, hb, nullptr, N_NODES, 128);

  for (int l = 0; l < 5; l++){
    // qkv = LN(h) @ [Wq|Wv|Wk] + bias  (LN fused, bf16 A)
    pgemm4<128, 384, bf16, true, false, false, bf16><<<Grow, B, 0, stream>>>(
        hb, g1 + l * DIM, b1 + l * DIM, Wqkvt + (size_t)l * QKVW * 128,
        bqkv + l * QKVW, nullptr, qkv, nullptr, N_NODES, QKVW);
    attn_kernel<<<12500, B, 0, stream>>>(rowptr, srclist, qkv, agg, N_NODES);
    // h = h + agg @ Wo + bo
    pgemm4<128, 128, bf16, false, false, true, bf16><<<Grow, B, 0, stream>>>(
        agg, nullptr, nullptr, Wot + (size_t)l * 128 * 128, bo + l * DIM,
        hb, hb, nullptr, N_NODES, 128);
    // mid = relu(LN(h) @ Wf1 + bf1)  (reference reuses g1/b1)
    pgemm4<128, 256, bf16, true, true, false, bf16><<<Grow, B, 0, stream>>>(
        hb, g1 + l * DIM, b1 + l * DIM, Wf1t + (size_t)l * 256 * 128,
        bf1 + l * 2 * DIM, nullptr, mid, nullptr, N_NODES, 256);
    // h = h + mid @ Wf2 + bf2 ; last layer dual-writes d_out (mid, f32 pre-round)
    float* out2 = (l == 4) ? (float*)d_out : nullptr;
    pgemm4<256, 128, bf16, false, false, true, bf16><<<Grow, B, 0, stream>>>(
        mid, nullptr, nullptr, Wf2t + (size_t)l * 128 * 256, bf2 + l * DIM,
        hb, hb, out2, N_NODES, 128);
  }

  // out = LN(h, g_out, b_out) @ Wout + bout  (M=40)
  pgemm4<128, 64, bf16, true, false, false, float><<<Grow, B, 0, stream>>>(
      hb, gout, bout_ln, Woutt, bout, nullptr, ((float*)d_out) + ND, nullptr, N_NODES, 40);
}